// Round 2
// baseline (859.385 us; speedup 1.0000x reference)
//
#include <hip/hip_runtime.h>
#include <hip/hip_cooperative_groups.h>

namespace cg = cooperative_groups;

#define N_ 16
#define C_ 256
#define F_ 64
#define T_ 256

typedef float f32x4 __attribute__((ext_vector_type(4)));

__device__ __forceinline__ float clampf(float v, float lo, float hi) {
    return fminf(fmaxf(v, lo), hi);
}

// integer code k = clip(rint(x*scale), -128, 127), returned as float
__device__ __forceinline__ float qcode(float x, float scale) {
    return clampf(rintf(x * scale), -128.f, 127.f);
}

// ---------------------------------------------------------------------------
// Fused cooperative kernel.
// grid = 1024 blocks x 256 thr (4 waves). wave <-> plane (n,c). lane <-> 4 t.
// Phase 1: freq dwconv + q + SSN + q -> aux codes in 64 packed-int VGPRs;
//          integer freq-sum -> mean codes; temporal conv + bn2 + relu -> z
//          codes (1 MiB) to ws.   [exact integer-code arithmetic]
// grid.sync()
// Phase 2: y(n,c,t) = q( sum_c' w1q[c,c'] * z[n,c',t] ) via L2-hot dword
//          loads (coalesced 256B/wave) + LDS-broadcast w1 codes.
// Phase 3: out = relu(q(aux + y)) from register-resident aux codes.
// All code-domain sums < 2^23 -> exact in fp32 for any op order.
// ---------------------------------------------------------------------------
__global__ __launch_bounds__(256, 4) void fused_kernel(
    const float* __restrict__ x,
    const float* __restrict__ wf,
    const float* __restrict__ ssn_g,
    const float* __restrict__ ssn_b,
    const float* __restrict__ ssn_mu,
    const float* __restrict__ ssn_va,
    const float* __restrict__ wt,
    const float* __restrict__ g2,
    const float* __restrict__ b2,
    const float* __restrict__ mu2,
    const float* __restrict__ va2,
    const float* __restrict__ w1,
    signed char* __restrict__ zt,     // ws: [N][C][T] int8 z codes (1 MiB)
    float* __restrict__ out)
{
    const int wave = threadIdx.x >> 6;
    const int lane = threadIdx.x & 63;
    const int plane = blockIdx.x * 4 + wave;     // n*C + c
    const int c = plane & (C_ - 1);
    const int n = plane >> 8;
    const int t0 = lane * 4;

    __shared__ float wq_l[4][C_];    // 4 KiB: w1 codes for this block's 4 rows

    // ---- stage w1 codes for this block's 4 output rows ----
    {
        const int w = threadIdx.x >> 6;
        const int j = (threadIdx.x & 63) * 4;
        const int crow = (blockIdx.x * 4 + w) & (C_ - 1);
        const f32x4 wv = *(const f32x4*)(w1 + crow * C_ + j);
        wq_l[w][j + 0] = qcode(wv.x, 128.f);
        wq_l[w][j + 1] = qcode(wv.y, 128.f);
        wq_l[w][j + 2] = qcode(wv.z, 128.f);
        wq_l[w][j + 3] = qcode(wv.w, 128.f);
    }
    __syncthreads();

    // =========================== phase 1 ====================================
    const f32x4* xp = (const f32x4*)(x + (size_t)plane * (F_ * T_) + t0);

    const float w0 = qcode(wf[c * 3 + 0], 128.f) * (1.f / 128.f);
    const float w1c = qcode(wf[c * 3 + 1], 128.f) * (1.f / 128.f);
    const float w2 = qcode(wf[c * 3 + 2], 128.f) * (1.f / 128.f);

    int auxq[F_];                     // packed char4 codes, static-indexed
    f32x4 xm; xm.x = 0.f; xm.y = 0.f; xm.z = 0.f; xm.w = 0.f;
    f32x4 x0 = xp[0];
    int s0 = 0, s1 = 0, s2 = 0, s3 = 0;

    #pragma unroll
    for (int g = 0; g < 4; ++g) {
        const int cs = c * 4 + g;
        const float m  = qcode(ssn_g[cs] * rsqrtf(ssn_va[cs] + 1e-5f), 128.f) * (1.f / 128.f);
        const float bc = qcode(ssn_b[cs] - ssn_mu[cs] * m, 16.f);   // bias CODE
        #pragma unroll
        for (int fi = 0; fi < 16; ++fi) {
            const int f = g * 16 + fi;
            f32x4 xn;
            if (f < F_ - 1) xn = xp[(f + 1) * (T_ / 4)];
            else            { xn.x = 0.f; xn.y = 0.f; xn.z = 0.f; xn.w = 0.f; }

            float ka0, ka1, ka2, ka3;
            {
                float conv = xm.x * w0 + x0.x * w1c + xn.x * w2;
                float q1c = clampf(rintf(conv * 16.f), -128.f, 127.f);
                ka0 = clampf(rintf(fmaf(q1c, m, bc)), -128.f, 127.f);
            }
            {
                float conv = xm.y * w0 + x0.y * w1c + xn.y * w2;
                float q1c = clampf(rintf(conv * 16.f), -128.f, 127.f);
                ka1 = clampf(rintf(fmaf(q1c, m, bc)), -128.f, 127.f);
            }
            {
                float conv = xm.z * w0 + x0.z * w1c + xn.z * w2;
                float q1c = clampf(rintf(conv * 16.f), -128.f, 127.f);
                ka2 = clampf(rintf(fmaf(q1c, m, bc)), -128.f, 127.f);
            }
            {
                float conv = xm.w * w0 + x0.w * w1c + xn.w * w2;
                float q1c = clampf(rintf(conv * 16.f), -128.f, 127.f);
                ka3 = clampf(rintf(fmaf(q1c, m, bc)), -128.f, 127.f);
            }
            const int i0 = (int)ka0, i1 = (int)ka1, i2 = (int)ka2, i3 = (int)ka3;
            s0 += i0; s1 += i1; s2 += i2; s3 += i3;
            auxq[f] = (i0 & 255) | ((i1 & 255) << 8) | ((i2 & 255) << 16) | (i3 << 24);
            xm = x0; x0 = xn;
        }
    }

    // ---- mean codes (8,4): clip(rint(sum/64)) ----
    const float m0 = clampf(rintf((float)s0 * (1.f / 64.f)), -128.f, 127.f);
    const float m1 = clampf(rintf((float)s1 * (1.f / 64.f)), -128.f, 127.f);
    const float m2v = clampf(rintf((float)s2 * (1.f / 64.f)), -128.f, 127.f);
    const float m3 = clampf(rintf((float)s3 * (1.f / 64.f)), -128.f, 127.f);

    // ---- temporal conv + bn2 + relu -> z codes (exact in code domain) ----
    float left  = __shfl_up(m3, 1);   if (lane == 0)  left  = 0.f;   // t-1
    float right = __shfl_down(m0, 1); if (lane == 63) right = 0.f;   // t+4
    {
        const float tw0 = qcode(wt[c * 3 + 0], 128.f) * (1.f / 128.f);
        const float tw1 = qcode(wt[c * 3 + 1], 128.f) * (1.f / 128.f);
        const float tw2 = qcode(wt[c * 3 + 2], 128.f) * (1.f / 128.f);
        const float mm2 = qcode(g2[c] * rsqrtf(va2[c] + 1e-5f), 128.f) * (1.f / 128.f);
        const float bb2 = qcode(b2[c] - mu2[c] * mm2, 16.f);

        float zc[4];
        const float a0 = left,  b0 = m0,  d0 = m1;
        const float a1 = m0,    b1 = m1,  d1 = m2v;
        const float a2 = m1,    b2_ = m2v, d2 = m3;
        const float a3 = m2v,   b3 = m3,  d3 = right;
        {
            float tcc = a0 * tw0 + b0 * tw1 + d0 * tw2;
            float q1c = clampf(rintf(tcc), -128.f, 127.f);
            zc[0] = fmaxf(clampf(rintf(fmaf(q1c, mm2, bb2)), -128.f, 127.f), 0.f);
        }
        {
            float tcc = a1 * tw0 + b1 * tw1 + d1 * tw2;
            float q1c = clampf(rintf(tcc), -128.f, 127.f);
            zc[1] = fmaxf(clampf(rintf(fmaf(q1c, mm2, bb2)), -128.f, 127.f), 0.f);
        }
        {
            float tcc = a2 * tw0 + b2_ * tw1 + d2 * tw2;
            float q1c = clampf(rintf(tcc), -128.f, 127.f);
            zc[2] = fmaxf(clampf(rintf(fmaf(q1c, mm2, bb2)), -128.f, 127.f), 0.f);
        }
        {
            float tcc = a3 * tw0 + b3 * tw1 + d3 * tw2;
            float q1c = clampf(rintf(tcc), -128.f, 127.f);
            zc[3] = fmaxf(clampf(rintf(fmaf(q1c, mm2, bb2)), -128.f, 127.f), 0.f);
        }
        const int z0 = (int)zc[0], z1 = (int)zc[1], z2 = (int)zc[2], z3 = (int)zc[3];
        *(int*)(zt + (size_t)plane * T_ + t0) =
            (z0 & 255) | ((z1 & 255) << 8) | ((z2 & 255) << 16) | (z3 << 24);
    }

    __threadfence();
    cg::this_grid().sync();

    // =========================== phase 2 ====================================
    // y codes for (n, c, t0..t0+3): sum over 256 c' of wcode * zcode.
    float ya0 = 0.f, ya1 = 0.f, ya2 = 0.f, ya3 = 0.f;
    {
        const signed char* zrow = zt + ((size_t)n * C_) * T_ + t0;
        const float* wqr = &wq_l[wave][0];
        #pragma unroll 8
        for (int cc = 0; cc < C_; ++cc) {
            const float wv = wqr[cc];
            const int u = *(const int*)(zrow + cc * T_);
            ya0 += wv * (float)(signed char)(u);
            ya1 += wv * (float)(signed char)(u >> 8);
            ya2 += wv * (float)(signed char)(u >> 16);
            ya3 += wv * (float)(u >> 24);
        }
    }
    const int iy0 = (int)clampf(rintf(ya0 * (1.f / 128.f)), -128.f, 127.f);
    const int iy1 = (int)clampf(rintf(ya1 * (1.f / 128.f)), -128.f, 127.f);
    const int iy2 = (int)clampf(rintf(ya2 * (1.f / 128.f)), -128.f, 127.f);
    const int iy3 = (int)clampf(rintf(ya3 * (1.f / 128.f)), -128.f, 127.f);

    // =========================== phase 3 ====================================
    f32x4* op = (f32x4*)(out + (size_t)plane * (F_ * T_) + t0);
    #pragma unroll
    for (int f = 0; f < F_; ++f) {
        const int u = auxq[f];
        const int o0 = min(127, max(0, ((int)(signed char)(u))       + iy0));
        const int o1 = min(127, max(0, ((int)(signed char)(u >> 8))  + iy1));
        const int o2 = min(127, max(0, ((int)(signed char)(u >> 16)) + iy2));
        const int o3 = min(127, max(0, (u >> 24)                     + iy3));
        f32x4 ov;
        ov.x = (float)o0 * (1.f / 16.f);
        ov.y = (float)o1 * (1.f / 16.f);
        ov.z = (float)o2 * (1.f / 16.f);
        ov.w = (float)o3 * (1.f / 16.f);
        op[f * (T_ / 4)] = ov;
    }
}

// ===========================================================================
// Fallback 3-kernel path (the R1-verified 526 µs version), used only if the
// cooperative launch is refused at runtime.
// ===========================================================================
__global__ __launch_bounds__(256) void aux_mean_kernel(
    const float* __restrict__ x,
    const float* __restrict__ wf,
    const float* __restrict__ ssn_g,
    const float* __restrict__ ssn_b,
    const float* __restrict__ ssn_mu,
    const float* __restrict__ ssn_va,
    signed char* __restrict__ aux_s8,
    signed char* __restrict__ mean_s8)
{
    const int wave = threadIdx.x >> 6;
    const int lane = threadIdx.x & 63;
    const int plane = blockIdx.x * 4 + wave;
    const int c = plane & (C_ - 1);
    const int t0 = lane * 4;

    const f32x4* xp = (const f32x4*)(x + (size_t)plane * (F_ * T_) + t0);
    signed char*  ap = aux_s8 + (size_t)plane * (F_ * T_) + t0;

    const float w0 = qcode(wf[c * 3 + 0], 128.f) * (1.f / 128.f);
    const float w1 = qcode(wf[c * 3 + 1], 128.f) * (1.f / 128.f);
    const float w2 = qcode(wf[c * 3 + 2], 128.f) * (1.f / 128.f);

    f32x4 xm; xm.x = 0.f; xm.y = 0.f; xm.z = 0.f; xm.w = 0.f;
    f32x4 x0 = xp[0];
    int s0 = 0, s1 = 0, s2 = 0, s3 = 0;

    int f = 0;
    for (int g = 0; g < 4; ++g) {
        const int cs = c * 4 + g;
        const float m  = qcode(ssn_g[cs] * rsqrtf(ssn_va[cs] + 1e-5f), 128.f) * (1.f / 128.f);
        const float bc = qcode(ssn_b[cs] - ssn_mu[cs] * m, 16.f);
        #pragma unroll 8
        for (int fi = 0; fi < 16; ++fi, ++f) {
            f32x4 xn;
            if (f < F_ - 1) xn = xp[(f + 1) * (T_ / 4)];
            else            { xn.x = 0.f; xn.y = 0.f; xn.z = 0.f; xn.w = 0.f; }
            float ka0, ka1, ka2, ka3;
            {
                float conv = xm.x * w0 + x0.x * w1 + xn.x * w2;
                float q1c = clampf(rintf(conv * 16.f), -128.f, 127.f);
                ka0 = clampf(rintf(fmaf(q1c, m, bc)), -128.f, 127.f);
            }
            {
                float conv = xm.y * w0 + x0.y * w1 + xn.y * w2;
                float q1c = clampf(rintf(conv * 16.f), -128.f, 127.f);
                ka1 = clampf(rintf(fmaf(q1c, m, bc)), -128.f, 127.f);
            }
            {
                float conv = xm.z * w0 + x0.z * w1 + xn.z * w2;
                float q1c = clampf(rintf(conv * 16.f), -128.f, 127.f);
                ka2 = clampf(rintf(fmaf(q1c, m, bc)), -128.f, 127.f);
            }
            {
                float conv = xm.w * w0 + x0.w * w1 + xn.w * w2;
                float q1c = clampf(rintf(conv * 16.f), -128.f, 127.f);
                ka3 = clampf(rintf(fmaf(q1c, m, bc)), -128.f, 127.f);
            }
            const int i0 = (int)ka0, i1 = (int)ka1, i2 = (int)ka2, i3 = (int)ka3;
            s0 += i0; s1 += i1; s2 += i2; s3 += i3;
            char4 cv;
            cv.x = (signed char)i0; cv.y = (signed char)i1;
            cv.z = (signed char)i2; cv.w = (signed char)i3;
            *(char4*)(ap + f * T_) = cv;
            xm = x0; x0 = xn;
        }
    }
    char4 mv;
    mv.x = (signed char)(int)clampf(rintf((float)s0 * (1.f / 64.f)), -128.f, 127.f);
    mv.y = (signed char)(int)clampf(rintf((float)s1 * (1.f / 64.f)), -128.f, 127.f);
    mv.z = (signed char)(int)clampf(rintf((float)s2 * (1.f / 64.f)), -128.f, 127.f);
    mv.w = (signed char)(int)clampf(rintf((float)s3 * (1.f / 64.f)), -128.f, 127.f);
    *(char4*)(mean_s8 + (size_t)plane * T_ + t0) = mv;
}

#define TT_ 16
#define ZP_ (TT_ + 4)
__global__ __launch_bounds__(256) void mean_path_kernel(
    const signed char* __restrict__ mean_s8,
    const float* __restrict__ wt,
    const float* __restrict__ g2,
    const float* __restrict__ b2,
    const float* __restrict__ mu2,
    const float* __restrict__ va2,
    const float* __restrict__ w1,
    signed char* __restrict__ y_s8)
{
    const int n = blockIdx.x >> 4;
    const int tt = (blockIdx.x & 15) * TT_;
    const int tid = threadIdx.x;
    __shared__ float z[C_][ZP_];
    {
        const int c = tid;
        const float wq0 = qcode(wt[c * 3 + 0], 128.f) * (1.f / 128.f);
        const float wq1 = qcode(wt[c * 3 + 1], 128.f) * (1.f / 128.f);
        const float wq2 = qcode(wt[c * 3 + 2], 128.f) * (1.f / 128.f);
        const float m2 = qcode(g2[c] * rsqrtf(va2[c] + 1e-5f), 128.f) * (1.f / 128.f);
        const float bc2 = qcode(b2[c] - mu2[c] * m2, 16.f);
        const signed char* mp = mean_s8 + (n * C_ + c) * T_;
        #pragma unroll
        for (int j = 0; j < TT_; ++j) {
            const int t = tt + j;
            const float a    = (t > 0)      ? (float)mp[t - 1] : 0.f;
            const float bmid =                (float)mp[t];
            const float d    = (t < T_ - 1) ? (float)mp[t + 1] : 0.f;
            float tcc = a * wq0 + bmid * wq1 + d * wq2;
            float q1c = clampf(rintf(tcc), -128.f, 127.f);
            float v   = clampf(rintf(fmaf(q1c, m2, bc2)), -128.f, 127.f);
            v = fmaxf(v, 0.f);
            z[c][j] = v * (1.f / 16.f);
        }
    }
    __syncthreads();
    {
        const int o = tid;
        float acc[TT_];
        #pragma unroll
        for (int j = 0; j < TT_; ++j) acc[j] = 0.f;
        const float* wrow = w1 + o * C_;
        for (int cbase = 0; cbase < C_; cbase += 4) {
            const f32x4 wv4 = *(const f32x4*)(wrow + cbase);
            const float wq[4] = {
                qcode(wv4.x, 128.f) * (1.f / 128.f),
                qcode(wv4.y, 128.f) * (1.f / 128.f),
                qcode(wv4.z, 128.f) * (1.f / 128.f),
                qcode(wv4.w, 128.f) * (1.f / 128.f)
            };
            #pragma unroll
            for (int u = 0; u < 4; ++u) {
                const float wv = wq[u];
                const f32x4 za = *(const f32x4*)&z[cbase + u][0];
                const f32x4 zb = *(const f32x4*)&z[cbase + u][4];
                const f32x4 zc = *(const f32x4*)&z[cbase + u][8];
                const f32x4 zd = *(const f32x4*)&z[cbase + u][12];
                acc[0]  += za.x * wv; acc[1]  += za.y * wv; acc[2]  += za.z * wv; acc[3]  += za.w * wv;
                acc[4]  += zb.x * wv; acc[5]  += zb.y * wv; acc[6]  += zb.z * wv; acc[7]  += zb.w * wv;
                acc[8]  += zc.x * wv; acc[9]  += zc.y * wv; acc[10] += zc.z * wv; acc[11] += zc.w * wv;
                acc[12] += zd.x * wv; acc[13] += zd.y * wv; acc[14] += zd.z * wv; acc[15] += zd.w * wv;
            }
        }
        signed char* yp = y_s8 + (n * C_ + o) * T_ + tt;
        #pragma unroll
        for (int j = 0; j < TT_; ++j) {
            yp[j] = (signed char)(int)qcode(acc[j], 16.f);
        }
    }
}

__global__ __launch_bounds__(256) void combine_kernel(
    const signed char* __restrict__ aux_s8,
    const signed char* __restrict__ y_s8,
    float* __restrict__ out)
{
    const int wave = threadIdx.x >> 6;
    const int lane = threadIdx.x & 63;
    const int plane = blockIdx.x * 4 + wave;
    const int t0 = lane * 4;

    const char4 yk = *(const char4*)(y_s8 + (size_t)plane * T_ + t0);
    const int y0 = yk.x, y1 = yk.y, y2 = yk.z, y3 = yk.w;

    const char4* ap = (const char4*)(aux_s8 + (size_t)plane * (F_ * T_) + t0);
    f32x4* op = (f32x4*)(out + (size_t)plane * (F_ * T_) + t0);

    #pragma unroll 8
    for (int f = 0; f < F_; ++f) {
        const char4 ak = ap[f * (T_ / 4)];
        const int o0 = min(127, max(0, (int)ak.x + y0));
        const int o1 = min(127, max(0, (int)ak.y + y1));
        const int o2 = min(127, max(0, (int)ak.z + y2));
        const int o3 = min(127, max(0, (int)ak.w + y3));
        f32x4 ov;
        ov.x = (float)o0 * (1.f / 16.f);
        ov.y = (float)o1 * (1.f / 16.f);
        ov.z = (float)o2 * (1.f / 16.f);
        ov.w = (float)o3 * (1.f / 16.f);
        op[f * (T_ / 4)] = ov;
    }
}

extern "C" void kernel_launch(void* const* d_in, const int* in_sizes, int n_in,
                              void* d_out, int out_size, void* d_ws, size_t ws_size,
                              hipStream_t stream) {
    const float* x       = (const float*)d_in[0];
    const float* w_freq  = (const float*)d_in[1];
    const float* ssn_g   = (const float*)d_in[2];
    const float* ssn_b   = (const float*)d_in[3];
    const float* ssn_mu  = (const float*)d_in[4];
    const float* ssn_va  = (const float*)d_in[5];
    const float* w_temp  = (const float*)d_in[6];
    const float* g2      = (const float*)d_in[7];
    const float* b2      = (const float*)d_in[8];
    const float* mu2     = (const float*)d_in[9];
    const float* va2     = (const float*)d_in[10];
    const float* w_1x1   = (const float*)d_in[11];
    float* out = (float*)d_out;

    signed char* zt      = (signed char*)d_ws;                        // 1 MiB
    signed char* aux_s8  = (signed char*)d_ws + (size_t)(1 << 20);    // fallback bufs
    signed char* mean_s8 = aux_s8 + (size_t)N_ * C_ * F_ * T_;
    signed char* y_s8    = mean_s8 + (size_t)N_ * C_ * T_;

    void* args[] = {
        (void*)&x, (void*)&w_freq, (void*)&ssn_g, (void*)&ssn_b,
        (void*)&ssn_mu, (void*)&ssn_va, (void*)&w_temp, (void*)&g2,
        (void*)&b2, (void*)&mu2, (void*)&va2, (void*)&w_1x1,
        (void*)&zt, (void*)&out
    };
    hipError_t err = hipLaunchCooperativeKernel(
        (const void*)fused_kernel, dim3(N_ * C_ / 4), dim3(256), args, 0, stream);

    if (err != hipSuccess) {
        // fallback: verified 3-kernel path
        dim3 blk(256);
        aux_mean_kernel<<<dim3(N_ * C_ / 4), blk, 0, stream>>>(
            x, w_freq, ssn_g, ssn_b, ssn_mu, ssn_va, aux_s8, mean_s8);
        mean_path_kernel<<<dim3(N_ * (T_ / TT_)), blk, 0, stream>>>(
            mean_s8, w_temp, g2, b2, mu2, va2, w_1x1, y_s8);
        combine_kernel<<<dim3(N_ * C_ / 4), blk, 0, stream>>>(
            aux_s8, y_s8, out);
    }
}

// Round 3
// 518.123 us; speedup vs baseline: 1.6587x; 1.6587x over previous
//
#include <hip/hip_runtime.h>

#define N_ 16
#define C_ 256
#define F_ 64
#define T_ 256

typedef float f32x4 __attribute__((ext_vector_type(4)));

__device__ __forceinline__ float clampf(float v, float lo, float hi) {
    return fminf(fmaxf(v, lo), hi);
}

// integer code k = clip(rint(x*scale), -128, 127), returned as float
__device__ __forceinline__ float qcode(float x, float scale) {
    return clampf(rintf(x * scale), -128.f, 127.f);
}

// ---------------------------------------------------------------------------
// k1: freq dwconv + q + SSN + q -> aux int8 codes; integer freq-sum -> mean.
// One wave per (n,c) plane; lane handles 4 consecutive t (float4 loads).
// R3: software-pipelined 4-row batches (double-buffered in regs) so each wave
// keeps 4-7 row loads (4-7 KiB) in flight instead of vmcnt(0)-ing every row.
// NOTE: no nontemporal hints — NT bypass races the harness's cached
// restore/poison ops (R4 post-timing divergence).
// ---------------------------------------------------------------------------
#define K1ROW(XM, X0, XN, FROW)                                                \
    {                                                                          \
        float ka0, ka1, ka2, ka3;                                              \
        {                                                                      \
            float conv = (XM).x * w0 + (X0).x * w1c + (XN).x * w2;             \
            float q1c = clampf(rintf(conv * 16.f), -128.f, 127.f);             \
            ka0 = clampf(rintf(fmaf(q1c, m, bc)), -128.f, 127.f);              \
        }                                                                      \
        {                                                                      \
            float conv = (XM).y * w0 + (X0).y * w1c + (XN).y * w2;             \
            float q1c = clampf(rintf(conv * 16.f), -128.f, 127.f);             \
            ka1 = clampf(rintf(fmaf(q1c, m, bc)), -128.f, 127.f);              \
        }                                                                      \
        {                                                                      \
            float conv = (XM).z * w0 + (X0).z * w1c + (XN).z * w2;             \
            float q1c = clampf(rintf(conv * 16.f), -128.f, 127.f);             \
            ka2 = clampf(rintf(fmaf(q1c, m, bc)), -128.f, 127.f);              \
        }                                                                      \
        {                                                                      \
            float conv = (XM).w * w0 + (X0).w * w1c + (XN).w * w2;             \
            float q1c = clampf(rintf(conv * 16.f), -128.f, 127.f);             \
            ka3 = clampf(rintf(fmaf(q1c, m, bc)), -128.f, 127.f);              \
        }                                                                      \
        const int i0 = (int)ka0, i1 = (int)ka1, i2 = (int)ka2, i3 = (int)ka3;  \
        s0 += i0; s1 += i1; s2 += i2; s3 += i3;                                \
        char4 cv;                                                              \
        cv.x = (signed char)i0; cv.y = (signed char)i1;                        \
        cv.z = (signed char)i2; cv.w = (signed char)i3;                        \
        *(char4*)(ap + (FROW) * T_) = cv;                                      \
    }

__global__ __launch_bounds__(256) void aux_mean_kernel(
    const float* __restrict__ x,
    const float* __restrict__ wf,
    const float* __restrict__ ssn_g,
    const float* __restrict__ ssn_b,
    const float* __restrict__ ssn_mu,
    const float* __restrict__ ssn_va,
    signed char* __restrict__ aux_s8,
    signed char* __restrict__ mean_s8)
{
    const int wave = threadIdx.x >> 6;
    const int lane = threadIdx.x & 63;
    const int plane = blockIdx.x * 4 + wave;     // n*C + c
    const int c = plane & (C_ - 1);
    const int t0 = lane * 4;

    const f32x4* xp = (const f32x4*)(x + (size_t)plane * (F_ * T_) + t0);
    signed char*  ap = aux_s8 + (size_t)plane * (F_ * T_) + t0;

    const float w0  = qcode(wf[c * 3 + 0], 128.f) * (1.f / 128.f);
    const float w1c = qcode(wf[c * 3 + 1], 128.f) * (1.f / 128.f);
    const float w2  = qcode(wf[c * 3 + 2], 128.f) * (1.f / 128.f);

    f32x4 zero; zero.x = 0.f; zero.y = 0.f; zero.z = 0.f; zero.w = 0.f;
    f32x4 xm = zero;
    f32x4 cur0 = xp[0 * (T_ / 4)];
    f32x4 cur1 = xp[1 * (T_ / 4)];
    f32x4 cur2 = xp[2 * (T_ / 4)];
    f32x4 cur3 = xp[3 * (T_ / 4)];
    int s0 = 0, s1 = 0, s2 = 0, s3 = 0;

    #pragma unroll
    for (int g = 0; g < 4; ++g) {
        const int cs = c * 4 + g;
        const float m  = qcode(ssn_g[cs] * rsqrtf(ssn_va[cs] + 1e-5f), 128.f) * (1.f / 128.f);
        const float bc = qcode(ssn_b[cs] - ssn_mu[cs] * m, 16.f);   // bias CODE
        #pragma unroll
        for (int bb = 0; bb < 4; ++bb) {
            const int base = g * 16 + bb * 4;
            f32x4 nxt0, nxt1, nxt2, nxt3;
            if (base + 4 < F_) {            // compile-time (fully unrolled)
                nxt0 = xp[(base + 4) * (T_ / 4)];
                nxt1 = xp[(base + 5) * (T_ / 4)];
                nxt2 = xp[(base + 6) * (T_ / 4)];
                nxt3 = xp[(base + 7) * (T_ / 4)];
            } else {
                nxt0 = zero; nxt1 = zero; nxt2 = zero; nxt3 = zero;
            }
            K1ROW(xm,   cur0, cur1, base + 0);
            K1ROW(cur0, cur1, cur2, base + 1);
            K1ROW(cur1, cur2, cur3, base + 2);
            K1ROW(cur2, cur3, nxt0, base + 3);
            xm = cur3;
            cur0 = nxt0; cur1 = nxt1; cur2 = nxt2; cur3 = nxt3;
        }
    }

    // mean over F, quantized to (8,4): code = clip(rint(sum_codes/64))
    char4 mv;
    mv.x = (signed char)(int)clampf(rintf((float)s0 * (1.f / 64.f)), -128.f, 127.f);
    mv.y = (signed char)(int)clampf(rintf((float)s1 * (1.f / 64.f)), -128.f, 127.f);
    mv.z = (signed char)(int)clampf(rintf((float)s2 * (1.f / 64.f)), -128.f, 127.f);
    mv.w = (signed char)(int)clampf(rintf((float)s3 * (1.f / 64.f)), -128.f, 127.f);
    *(char4*)(mean_s8 + (size_t)plane * T_ + t0) = mv;
}

// ---------------------------------------------------------------------------
// k2: temporal conv + q + bn2 + q + relu + 1x1 conv + q on the (N,C,1,T) mean.
// z transposed to [C][TT+4] so phase-2 inner reads are broadcast ds_read_b128.
// Phase-2 weight row loaded as float4 (verified R1).
// ---------------------------------------------------------------------------
#define TT_ 16
#define ZP_ (TT_ + 4)
__global__ __launch_bounds__(256) void mean_path_kernel(
    const signed char* __restrict__ mean_s8,
    const float* __restrict__ wt,
    const float* __restrict__ g2,
    const float* __restrict__ b2,
    const float* __restrict__ mu2,
    const float* __restrict__ va2,
    const float* __restrict__ w1,
    signed char* __restrict__ y_s8)
{
    const int n = blockIdx.x >> 4;
    const int tt = (blockIdx.x & 15) * TT_;
    const int tid = threadIdx.x;

    __shared__ float z[C_][ZP_];   // 20 KiB, rows 80B apart (16B aligned)

    {   // phase 1: c = tid
        const int c = tid;
        const float wq0 = qcode(wt[c * 3 + 0], 128.f) * (1.f / 128.f);
        const float wq1 = qcode(wt[c * 3 + 1], 128.f) * (1.f / 128.f);
        const float wq2 = qcode(wt[c * 3 + 2], 128.f) * (1.f / 128.f);
        const float m2 = qcode(g2[c] * rsqrtf(va2[c] + 1e-5f), 128.f) * (1.f / 128.f);
        const float bc2 = qcode(b2[c] - mu2[c] * m2, 16.f);   // bias code
        const signed char* mp = mean_s8 + (n * C_ + c) * T_;
        #pragma unroll
        for (int j = 0; j < TT_; ++j) {
            const int t = tt + j;
            const float a    = (t > 0)      ? (float)mp[t - 1] : 0.f;   // codes
            const float bmid =                (float)mp[t];
            const float d    = (t < T_ - 1) ? (float)mp[t + 1] : 0.f;
            // conv on values = (code/16); q(.,16) code = clamp(rint(conv*16))
            float tcc = a * wq0 + bmid * wq1 + d * wq2;          // = conv*16
            float q1c = clampf(rintf(tcc), -128.f, 127.f);       // code of q(tc)
            float v   = clampf(rintf(fmaf(q1c, m2, bc2)), -128.f, 127.f); // code
            v = fmaxf(v, 0.f);               // relu on codes
            z[c][j] = v * (1.f / 16.f);      // value for the 1x1 dot
        }
    }
    __syncthreads();
    {   // phase 2: o = tid
        const int o = tid;
        float acc[TT_];
        #pragma unroll
        for (int j = 0; j < TT_; ++j) acc[j] = 0.f;
        const float* wrow = w1 + o * C_;
        for (int cbase = 0; cbase < C_; cbase += 4) {
            const f32x4 wv4 = *(const f32x4*)(wrow + cbase);
            const float wq[4] = {
                qcode(wv4.x, 128.f) * (1.f / 128.f),
                qcode(wv4.y, 128.f) * (1.f / 128.f),
                qcode(wv4.z, 128.f) * (1.f / 128.f),
                qcode(wv4.w, 128.f) * (1.f / 128.f)
            };
            #pragma unroll
            for (int u = 0; u < 4; ++u) {
                const float wv = wq[u];
                const f32x4 za = *(const f32x4*)&z[cbase + u][0];
                const f32x4 zb = *(const f32x4*)&z[cbase + u][4];
                const f32x4 zc = *(const f32x4*)&z[cbase + u][8];
                const f32x4 zd = *(const f32x4*)&z[cbase + u][12];
                acc[0]  += za.x * wv; acc[1]  += za.y * wv; acc[2]  += za.z * wv; acc[3]  += za.w * wv;
                acc[4]  += zb.x * wv; acc[5]  += zb.y * wv; acc[6]  += zb.z * wv; acc[7]  += zb.w * wv;
                acc[8]  += zc.x * wv; acc[9]  += zc.y * wv; acc[10] += zc.z * wv; acc[11] += zc.w * wv;
                acc[12] += zd.x * wv; acc[13] += zd.y * wv; acc[14] += zd.z * wv; acc[15] += zd.w * wv;
            }
        }
        signed char* yp = y_s8 + (n * C_ + o) * T_ + tt;
        #pragma unroll
        for (int j = 0; j < TT_; ++j) {
            yp[j] = (signed char)(int)qcode(acc[j], 16.f);
        }
    }
}

// ---------------------------------------------------------------------------
// k3: out = relu(quant(aux + y)) = clamp(ka + ky, 0, 127) / 16 -> fp32.
// R3: 8-row register batches (double-buffered) so each wave keeps 8 aux-row
// loads in flight; stores stream behind.
// ---------------------------------------------------------------------------
__global__ __launch_bounds__(256) void combine_kernel(
    const signed char* __restrict__ aux_s8,
    const signed char* __restrict__ y_s8,
    float* __restrict__ out)
{
    const int wave = threadIdx.x >> 6;
    const int lane = threadIdx.x & 63;
    const int plane = blockIdx.x * 4 + wave;
    const int t0 = lane * 4;

    const char4 yk = *(const char4*)(y_s8 + (size_t)plane * T_ + t0);
    const int y0 = yk.x, y1 = yk.y, y2 = yk.z, y3 = yk.w;

    const int* ap = (const int*)(aux_s8 + (size_t)plane * (F_ * T_) + t0);
    f32x4* op = (f32x4*)(out + (size_t)plane * (F_ * T_) + t0);

    int cura[8], nxta[8];
    #pragma unroll
    for (int i = 0; i < 8; ++i) cura[i] = ap[i * (T_ / 4)];

    #pragma unroll
    for (int b = 0; b < 8; ++b) {
        if (b < 7) {                     // compile-time (fully unrolled)
            #pragma unroll
            for (int i = 0; i < 8; ++i)
                nxta[i] = ap[(b * 8 + 8 + i) * (T_ / 4)];
        }
        #pragma unroll
        for (int i = 0; i < 8; ++i) {
            const int u = cura[i];
            const int o0 = min(127, max(0, ((int)(signed char)(u))       + y0));
            const int o1 = min(127, max(0, ((int)(signed char)(u >> 8))  + y1));
            const int o2 = min(127, max(0, ((int)(signed char)(u >> 16)) + y2));
            const int o3 = min(127, max(0, (u >> 24)                     + y3));
            f32x4 ov;
            ov.x = (float)o0 * (1.f / 16.f);
            ov.y = (float)o1 * (1.f / 16.f);
            ov.z = (float)o2 * (1.f / 16.f);
            ov.w = (float)o3 * (1.f / 16.f);
            op[(b * 8 + i) * (T_ / 4)] = ov;
        }
        #pragma unroll
        for (int i = 0; i < 8; ++i) cura[i] = nxta[i];
    }
}

extern "C" void kernel_launch(void* const* d_in, const int* in_sizes, int n_in,
                              void* d_out, int out_size, void* d_ws, size_t ws_size,
                              hipStream_t stream) {
    const float* x       = (const float*)d_in[0];
    const float* w_freq  = (const float*)d_in[1];
    const float* ssn_g   = (const float*)d_in[2];
    const float* ssn_b   = (const float*)d_in[3];
    const float* ssn_mu  = (const float*)d_in[4];
    const float* ssn_va  = (const float*)d_in[5];
    const float* w_temp  = (const float*)d_in[6];
    const float* g2      = (const float*)d_in[7];
    const float* b2      = (const float*)d_in[8];
    const float* mu2     = (const float*)d_in[9];
    const float* va2     = (const float*)d_in[10];
    const float* w_1x1   = (const float*)d_in[11];
    float* out = (float*)d_out;

    signed char* aux_s8  = (signed char*)d_ws;                        // 64 MiB
    signed char* mean_s8 = aux_s8 + (size_t)N_ * C_ * F_ * T_;        // 1 MiB
    signed char* y_s8    = mean_s8 + (size_t)N_ * C_ * T_;            // 1 MiB

    dim3 blk(256);
    aux_mean_kernel<<<dim3(N_ * C_ / 4), blk, 0, stream>>>(
        x, w_freq, ssn_g, ssn_b, ssn_mu, ssn_va, aux_s8, mean_s8);
    mean_path_kernel<<<dim3(N_ * (T_ / TT_)), blk, 0, stream>>>(
        mean_s8, w_temp, g2, b2, mu2, va2, w_1x1, y_s8);
    combine_kernel<<<dim3(N_ * C_ / 4), blk, 0, stream>>>(
        aux_s8, y_s8, out);
}